// Round 1
// baseline (674.458 us; speedup 1.0000x reference)
//
#include <hip/hip_runtime.h>
#include <hip/hip_bf16.h>

#define N_NODES 80000
#define N_EDGES 1280000
#define N_FEAT 4
#define HIDDEN 64
#define N_GRAPHS 64
#define BN_EPS 1e-5f

// ---------------------------------------------------------------------------
// BN (eval mode): h0[n][k] = (x - mean[k]) * gamma[k]*rsqrt(var[k]+eps) + beta[k]
__global__ void bn_kernel(const float* __restrict__ x,
                          const float* __restrict__ gamma,
                          const float* __restrict__ beta,
                          const float* __restrict__ mean,
                          const float* __restrict__ var,
                          float* __restrict__ h0) {
    int i = blockIdx.x * blockDim.x + threadIdx.x;
    if (i < N_NODES * N_FEAT) {
        int k = i & 3;
        float scale = gamma[k] * rsqrtf(var[k] + BN_EPS);
        h0[i] = (x[i] - mean[k]) * scale + beta[k];
    }
}

// ---------------------------------------------------------------------------
// CSR build: count in-degree per dst
__global__ void count_kernel(const int* __restrict__ dst, int* __restrict__ deg) {
    int e = blockIdx.x * blockDim.x + threadIdx.x;
    if (e < N_EDGES) atomicAdd(&deg[dst[e]], 1);
}

// Exclusive scan over deg[0..N) -> rowstart[0..N], also init cursor = rowstart
__global__ __launch_bounds__(1024) void scan_kernel(const int* __restrict__ deg,
                                                    int* __restrict__ rowstart,
                                                    int* __restrict__ cursor) {
    __shared__ int sums[1024];
    const int t = threadIdx.x;
    const int CH = (N_NODES + 1023) / 1024;  // 79
    int lo = t * CH;
    int hi = lo + CH; if (hi > N_NODES) hi = N_NODES;
    int s = 0;
    for (int i = lo; i < hi; ++i) s += deg[i];
    sums[t] = s;
    __syncthreads();
    // Hillis-Steele inclusive scan
    for (int off = 1; off < 1024; off <<= 1) {
        int v = (t >= off) ? sums[t - off] : 0;
        __syncthreads();
        sums[t] += v;
        __syncthreads();
    }
    int run = (t == 0) ? 0 : sums[t - 1];
    for (int i = lo; i < hi; ++i) {
        rowstart[i] = run;
        cursor[i] = run;
        run += deg[i];
    }
    if (t == 1023) rowstart[N_NODES] = run;  // == N_EDGES
}

// Fill CSR: csr_src[rowstart[dst] + pos] = src
__global__ void fill_kernel(const int* __restrict__ src, const int* __restrict__ dst,
                            int* __restrict__ cursor, int* __restrict__ csr) {
    int e = blockIdx.x * blockDim.x + threadIdx.x;
    if (e < N_EDGES) {
        int d = dst[e];
        int p = atomicAdd(&cursor[d], 1);
        csr[p] = src[e];
    }
}

// ---------------------------------------------------------------------------
// Layer 1 (in=4, out=64), fused aggregate + transform + relu.
// One wave per node; lane j computes output feature j.
__global__ __launch_bounds__(1024) void layer1_kernel(
        const float* __restrict__ h0, float* __restrict__ h1,
        const int* __restrict__ rowstart, const int* __restrict__ csr,
        const float* __restrict__ Wrel, const float* __restrict__ Wroot,
        const float* __restrict__ b) {
    const int lane = threadIdx.x & 63;
    const int wid = threadIdx.x >> 6;
    float wrel[4], wroot[4];
#pragma unroll
    for (int k = 0; k < 4; ++k) {
        wrel[k] = Wrel[k * 64 + lane];
        wroot[k] = Wroot[k * 64 + lane];
    }
    const float bj = b[lane];
    const int sub = lane >> 2;  // 0..15: which edge slot
    const int f = lane & 3;     // which feature
    const int nW = gridDim.x * 16;
    for (int n0 = blockIdx.x * 16 + wid; n0 < N_NODES; n0 += nW) {
        const int node = __builtin_amdgcn_readfirstlane(n0);
        const int e0 = rowstart[node], e1 = rowstart[node + 1];
        float part = 0.f;
        for (int e = e0 + sub; e < e1; e += 16) {
            int s = csr[e];
            part += h0[s * 4 + f];
        }
        // reduce across the 16 edge-slots (lanes sharing lane&3)
        part += __shfl_xor(part, 4);
        part += __shfl_xor(part, 8);
        part += __shfl_xor(part, 16);
        part += __shfl_xor(part, 32);
        float a0 = __shfl(part, 0), a1 = __shfl(part, 1);
        float a2 = __shfl(part, 2), a3 = __shfl(part, 3);
        float x0 = h0[node * 4 + 0], x1 = h0[node * 4 + 1];
        float x2 = h0[node * 4 + 2], x3 = h0[node * 4 + 3];
        float out = bj + a0 * wrel[0] + a1 * wrel[1] + a2 * wrel[2] + a3 * wrel[3]
                  + x0 * wroot[0] + x1 * wroot[1] + x2 * wroot[2] + x3 * wroot[3];
        h1[node * 64 + lane] = fmaxf(out, 0.f);
    }
}

// ---------------------------------------------------------------------------
// Layer with in=out=64, fused aggregate + transform (+ optional relu).
// One wave per node; lane j owns feature j. Edge gathers are fully coalesced
// 256B row reads. Dense part: stage agg/h rows in LDS (wave-synchronous),
// broadcast-read as float4, W columns from LDS at stride-1 (2-way = free).
__global__ __launch_bounds__(1024) void layer64_kernel(
        const float* __restrict__ hin, float* __restrict__ hout,
        const int* __restrict__ rowstart, const int* __restrict__ csr,
        const float* __restrict__ Wrel, const float* __restrict__ Wroot,
        const float* __restrict__ b, int relu) {
    __shared__ float sW[2][64][64];   // 32KB
    __shared__ float sV[16][2][64];   // per-wave staging: [agg, h]
    const int lane = threadIdx.x & 63;
    const int wid = threadIdx.x >> 6;
    for (int i = threadIdx.x; i < 64 * 64; i += 1024) {
        sW[0][i >> 6][i & 63] = Wrel[i];
        sW[1][i >> 6][i & 63] = Wroot[i];
    }
    __syncthreads();
    const float bj = b[lane];
    const int nW = gridDim.x * 16;
    for (int n0 = blockIdx.x * 16 + wid; n0 < N_NODES; n0 += nW) {
        const int node = __builtin_amdgcn_readfirstlane(n0);
        const int e0 = rowstart[node], e1 = rowstart[node + 1];
        float agg = 0.f;
        for (int e = e0; e < e1; ++e) {
            int s = csr[e];                 // uniform (scalar) load
            agg += hin[s * 64 + lane];      // coalesced 256B row
        }
        float hv = hin[node * 64 + lane];
        sV[wid][0][lane] = agg;
        sV[wid][1][lane] = hv;
        // wave-synchronous: ensure the wave's own LDS writes have landed
        asm volatile("s_waitcnt lgkmcnt(0)" ::: "memory");
        float out = bj;
        const float4* aggv = (const float4*)&sV[wid][0][0];
        const float4* hvv = (const float4*)&sV[wid][1][0];
#pragma unroll
        for (int k4 = 0; k4 < 16; ++k4) {
            float4 a4 = aggv[k4];   // broadcast ds_read_b128
            float4 h4 = hvv[k4];
            int k = k4 * 4;
            out += a4.x * sW[0][k + 0][lane] + a4.y * sW[0][k + 1][lane]
                 + a4.z * sW[0][k + 2][lane] + a4.w * sW[0][k + 3][lane]
                 + h4.x * sW[1][k + 0][lane] + h4.y * sW[1][k + 1][lane]
                 + h4.z * sW[1][k + 2][lane] + h4.w * sW[1][k + 3][lane];
        }
        if (relu) out = fmaxf(out, 0.f);
        hout[node * 64 + lane] = out;
    }
}

// ---------------------------------------------------------------------------
// Mean-pool per graph. batch is sorted; each wave takes a contiguous chunk,
// accumulates in registers, flushes with atomics only at graph boundaries.
__global__ void pool_kernel(const float* __restrict__ h3, const int* __restrict__ batch,
                            float* __restrict__ pool, float* __restrict__ cnt) {
    const int lane = threadIdx.x & 63;
    const int gw = (blockIdx.x * blockDim.x + threadIdx.x) >> 6;
    const int nW = (gridDim.x * blockDim.x) >> 6;
    const int chunk = (N_NODES + nW - 1) / nW;
    int n0 = gw * chunk;
    int n1 = n0 + chunk; if (n1 > N_NODES) n1 = N_NODES;
    if (n0 >= N_NODES) return;
    float acc = 0.f;
    int cur = batch[n0];
    int cl = 0;
    for (int n = n0; n < n1; ++n) {
        int g = batch[n];
        if (g != cur) {
            atomicAdd(&pool[cur * 64 + lane], acc);
            if (lane == 0) atomicAdd(&cnt[cur], (float)cl);
            acc = 0.f; cl = 0; cur = g;
        }
        acc += h3[(size_t)n * 64 + lane];
        cl++;
    }
    atomicAdd(&pool[cur * 64 + lane], acc);
    if (lane == 0) atomicAdd(&cnt[cur], (float)cl);
}

// Final head: out[g][c] = (pool[g]/cnt[g]) @ lin_W + lin_b
__global__ void head_kernel(const float* __restrict__ pool, const float* __restrict__ cnt,
                            const float* __restrict__ linW, const float* __restrict__ linb,
                            float* __restrict__ out) {
    int g = threadIdx.x >> 1;
    int c = threadIdx.x & 1;
    if (g < N_GRAPHS) {
        float inv = 1.0f / fmaxf(cnt[g], 1.0f);
        float acc = linb[c];
        for (int j = 0; j < 64; ++j) acc += pool[g * 64 + j] * inv * linW[j * 2 + c];
        out[g * 2 + c] = acc;
    }
}

// ---------------------------------------------------------------------------
extern "C" void kernel_launch(void* const* d_in, const int* in_sizes, int n_in,
                              void* d_out, int out_size, void* d_ws, size_t ws_size,
                              hipStream_t stream) {
    const float* x = (const float*)d_in[0];
    const int* edge_index = (const int*)d_in[1];
    const int* batch = (const int*)d_in[2];
    const float* bn_gamma = (const float*)d_in[3];
    const float* bn_beta = (const float*)d_in[4];
    const float* bn_mean = (const float*)d_in[5];
    const float* bn_var = (const float*)d_in[6];
    const float* W1_rel = (const float*)d_in[7];
    const float* b1_rel = (const float*)d_in[8];
    const float* W1_root = (const float*)d_in[9];
    const float* W2_rel = (const float*)d_in[10];
    const float* b2_rel = (const float*)d_in[11];
    const float* W2_root = (const float*)d_in[12];
    const float* W3_rel = (const float*)d_in[13];
    const float* b3_rel = (const float*)d_in[14];
    const float* W3_root = (const float*)d_in[15];
    const float* lin_W = (const float*)d_in[16];
    const float* lin_b = (const float*)d_in[17];
    float* out = (float*)d_out;

    const int* e_src = edge_index;
    const int* e_dst = edge_index + N_EDGES;

    // workspace layout
    float* ws_f = (float*)d_ws;
    float* h0 = ws_f;                       // 320000
    float* h1 = h0 + 320000;                // 5120000
    float* h2 = h1 + 5120000;               // 5120000
    float* pool = h2 + 5120000;             // 4096
    float* cnt = pool + 4096;               // 64
    int* deg = (int*)(cnt + 64);            // 80000
    int* rowstart = deg + 80000;            // 80001
    int* cursor = rowstart + 80001;         // 80000
    int* csr = cursor + 80000;              // 1280000
    float* h3 = h1;                         // alias: h1 dead once h2 computed

    // zero the accumulators we rely on
    hipMemsetAsync(deg, 0, (size_t)N_NODES * sizeof(int), stream);
    hipMemsetAsync(pool, 0, (size_t)(4096 + 64) * sizeof(float), stream);

    // BN
    bn_kernel<<<(N_NODES * N_FEAT + 255) / 256, 256, 0, stream>>>(
        x, bn_gamma, bn_beta, bn_mean, bn_var, h0);

    // CSR build
    count_kernel<<<(N_EDGES + 255) / 256, 256, 0, stream>>>(e_dst, deg);
    scan_kernel<<<1, 1024, 0, stream>>>(deg, rowstart, cursor);
    fill_kernel<<<(N_EDGES + 255) / 256, 256, 0, stream>>>(e_src, e_dst, cursor, csr);

    // Layer 1: h1 = relu(conv(h0))
    layer1_kernel<<<512, 1024, 0, stream>>>(h0, h1, rowstart, csr, W1_rel, W1_root, b1_rel);
    // Layer 2: h2 = relu(conv(h1))
    layer64_kernel<<<512, 1024, 0, stream>>>(h1, h2, rowstart, csr, W2_rel, W2_root, b2_rel, 1);
    // Layer 3: h3 = conv(h2)   (no relu), h3 aliases h1
    layer64_kernel<<<512, 1024, 0, stream>>>(h2, h3, rowstart, csr, W3_rel, W3_root, b3_rel, 0);

    // Pool + head
    pool_kernel<<<256, 256, 0, stream>>>(h3, batch, pool, cnt);
    head_kernel<<<1, 128, 0, stream>>>(pool, cnt, lin_W, lin_b, out);
}

// Round 2
// 503.061 us; speedup vs baseline: 1.3407x; 1.3407x over previous
//
#include <hip/hip_runtime.h>
#include <hip/hip_bf16.h>

#define N_NODES 80000
#define N_EDGES 1280000
#define N_FEAT 4
#define HIDDEN 64
#define N_GRAPHS 64
#define BN_EPS 1e-5f

#define SCAN_CH 256
#define SCAN_NB ((N_NODES + SCAN_CH - 1) / SCAN_CH)   // 313

// ---------------------------------------------------------------------------
// BN (eval mode): h0[n][k] = (x - mean[k]) * gamma[k]*rsqrt(var[k]+eps) + beta[k]
__global__ void bn_kernel(const float* __restrict__ x,
                          const float* __restrict__ gamma,
                          const float* __restrict__ beta,
                          const float* __restrict__ mean,
                          const float* __restrict__ var,
                          float* __restrict__ h0) {
    int i = blockIdx.x * blockDim.x + threadIdx.x;
    if (i < N_NODES * N_FEAT) {
        int k = i & 3;
        float scale = gamma[k] * rsqrtf(var[k] + BN_EPS);
        h0[i] = (x[i] - mean[k]) * scale + beta[k];
    }
}

// ---------------------------------------------------------------------------
// CSR build: count in-degree per dst
__global__ void count_kernel(const int* __restrict__ dst, int* __restrict__ deg) {
    int e = blockIdx.x * blockDim.x + threadIdx.x;
    if (e < N_EDGES) atomicAdd(&deg[dst[e]], 1);
}

// Device-wide exclusive scan, pass 1: per-block reduce of deg chunks
__global__ void scan_pass1(const int* __restrict__ deg, int* __restrict__ bsum) {
    __shared__ int s[4];
    int i = blockIdx.x * SCAN_CH + threadIdx.x;
    int v = (i < N_NODES) ? deg[i] : 0;
#pragma unroll
    for (int off = 1; off < 64; off <<= 1) v += __shfl_xor(v, off);
    if ((threadIdx.x & 63) == 0) s[threadIdx.x >> 6] = v;
    __syncthreads();
    if (threadIdx.x == 0) bsum[blockIdx.x] = s[0] + s[1] + s[2] + s[3];
}

// pass 2: scan the 313 block sums (one small block) -> exclusive offsets
__global__ __launch_bounds__(512) void scan_pass2(const int* __restrict__ bsum,
                                                  int* __restrict__ boff) {
    __shared__ int s[512];
    const int t = threadIdx.x;
    int v = (t < SCAN_NB) ? bsum[t] : 0;
    s[t] = v;
    __syncthreads();
    for (int off = 1; off < 512; off <<= 1) {
        int u = (t >= off) ? s[t - off] : 0;
        __syncthreads();
        s[t] += u;
        __syncthreads();
    }
    if (t < SCAN_NB) boff[t] = s[t] - v;   // exclusive
}

// pass 3: block-local inclusive scan + block offset -> rowstart / cursor
__global__ void scan_pass3(const int* __restrict__ deg, const int* __restrict__ boff,
                           int* __restrict__ rowstart, int* __restrict__ cursor) {
    __shared__ int s[SCAN_CH];
    const int t = threadIdx.x;
    int i = blockIdx.x * SCAN_CH + t;
    int v = (i < N_NODES) ? deg[i] : 0;
    s[t] = v;
    __syncthreads();
    for (int off = 1; off < SCAN_CH; off <<= 1) {
        int u = (t >= off) ? s[t - off] : 0;
        __syncthreads();
        s[t] += u;
        __syncthreads();
    }
    if (i < N_NODES) {
        int excl = boff[blockIdx.x] + s[t] - v;
        rowstart[i] = excl;
        cursor[i] = excl;
        if (i == N_NODES - 1) rowstart[N_NODES] = boff[blockIdx.x] + s[t];
    }
}

// Fill CSR: csr_src[rowstart[dst] + pos] = src
__global__ void fill_kernel(const int* __restrict__ src, const int* __restrict__ dst,
                            int* __restrict__ cursor, int* __restrict__ csr) {
    int e = blockIdx.x * blockDim.x + threadIdx.x;
    if (e < N_EDGES) {
        int d = dst[e];
        int p = atomicAdd(&cursor[d], 1);
        csr[p] = src[e];
    }
}

// ---------------------------------------------------------------------------
// Layer 1 (in=4, out=64), fused aggregate + transform + relu.
// One wave per node; lane j computes output feature j.
__global__ __launch_bounds__(1024) void layer1_kernel(
        const float* __restrict__ h0, float* __restrict__ h1,
        const int* __restrict__ rowstart, const int* __restrict__ csr,
        const float* __restrict__ Wrel, const float* __restrict__ Wroot,
        const float* __restrict__ b) {
    const int lane = threadIdx.x & 63;
    const int wid = threadIdx.x >> 6;
    float wrel[4], wroot[4];
#pragma unroll
    for (int k = 0; k < 4; ++k) {
        wrel[k] = Wrel[k * 64 + lane];
        wroot[k] = Wroot[k * 64 + lane];
    }
    const float bj = b[lane];
    const int sub = lane >> 2;  // 0..15: which edge slot
    const int f = lane & 3;     // which feature
    const int nW = gridDim.x * 16;
    for (int n0 = blockIdx.x * 16 + wid; n0 < N_NODES; n0 += nW) {
        const int node = __builtin_amdgcn_readfirstlane(n0);
        const int e0 = rowstart[node], e1 = rowstart[node + 1];
        float part = 0.f;
        for (int e = e0 + sub; e < e1; e += 16) {
            int s = csr[e];
            part += h0[s * 4 + f];
        }
        // reduce across the 16 edge-slots (lanes sharing lane&3)
        part += __shfl_xor(part, 4);
        part += __shfl_xor(part, 8);
        part += __shfl_xor(part, 16);
        part += __shfl_xor(part, 32);
        float a0 = __shfl(part, 0), a1 = __shfl(part, 1);
        float a2 = __shfl(part, 2), a3 = __shfl(part, 3);
        float x0 = h0[node * 4 + 0], x1 = h0[node * 4 + 1];
        float x2 = h0[node * 4 + 2], x3 = h0[node * 4 + 3];
        float out = bj + a0 * wrel[0] + a1 * wrel[1] + a2 * wrel[2] + a3 * wrel[3]
                  + x0 * wroot[0] + x1 * wroot[1] + x2 * wroot[2] + x3 * wroot[3];
        h1[node * 64 + lane] = fmaxf(out, 0.f);
    }
}

// ---------------------------------------------------------------------------
// Layer with in=out=64, fused aggregate + transform (+ optional relu).
__global__ __launch_bounds__(1024) void layer64_kernel(
        const float* __restrict__ hin, float* __restrict__ hout,
        const int* __restrict__ rowstart, const int* __restrict__ csr,
        const float* __restrict__ Wrel, const float* __restrict__ Wroot,
        const float* __restrict__ b, int relu) {
    __shared__ float sW[2][64][64];   // 32KB
    __shared__ float sV[16][2][64];   // per-wave staging: [agg, h]
    const int lane = threadIdx.x & 63;
    const int wid = threadIdx.x >> 6;
    for (int i = threadIdx.x; i < 64 * 64; i += 1024) {
        sW[0][i >> 6][i & 63] = Wrel[i];
        sW[1][i >> 6][i & 63] = Wroot[i];
    }
    __syncthreads();
    const float bj = b[lane];
    const int nW = gridDim.x * 16;
    for (int n0 = blockIdx.x * 16 + wid; n0 < N_NODES; n0 += nW) {
        const int node = __builtin_amdgcn_readfirstlane(n0);
        const int e0 = rowstart[node], e1 = rowstart[node + 1];
        float agg = 0.f;
        for (int e = e0; e < e1; ++e) {
            int s = csr[e];                 // uniform (scalar) load
            agg += hin[s * 64 + lane];      // coalesced 256B row
        }
        float hv = hin[node * 64 + lane];
        sV[wid][0][lane] = agg;
        sV[wid][1][lane] = hv;
        // wave-synchronous: ensure the wave's own LDS writes have landed
        asm volatile("s_waitcnt lgkmcnt(0)" ::: "memory");
        float out = bj;
        const float4* aggv = (const float4*)&sV[wid][0][0];
        const float4* hvv = (const float4*)&sV[wid][1][0];
#pragma unroll
        for (int k4 = 0; k4 < 16; ++k4) {
            float4 a4 = aggv[k4];   // broadcast ds_read_b128
            float4 h4 = hvv[k4];
            int k = k4 * 4;
            out += a4.x * sW[0][k + 0][lane] + a4.y * sW[0][k + 1][lane]
                 + a4.z * sW[0][k + 2][lane] + a4.w * sW[0][k + 3][lane]
                 + h4.x * sW[1][k + 0][lane] + h4.y * sW[1][k + 1][lane]
                 + h4.z * sW[1][k + 2][lane] + h4.w * sW[1][k + 3][lane];
        }
        if (relu) out = fmaxf(out, 0.f);
        hout[node * 64 + lane] = out;
    }
}

// ---------------------------------------------------------------------------
// Mean-pool per graph. batch is sorted; each wave takes a contiguous chunk,
// accumulates in registers, flushes with atomics only at graph boundaries.
__global__ void pool_kernel(const float* __restrict__ h3, const int* __restrict__ batch,
                            float* __restrict__ pool, float* __restrict__ cnt) {
    const int lane = threadIdx.x & 63;
    const int gw = (blockIdx.x * blockDim.x + threadIdx.x) >> 6;
    const int nW = (gridDim.x * blockDim.x) >> 6;
    const int chunk = (N_NODES + nW - 1) / nW;
    int n0 = gw * chunk;
    int n1 = n0 + chunk; if (n1 > N_NODES) n1 = N_NODES;
    if (n0 >= N_NODES) return;
    float acc = 0.f;
    int cur = batch[n0];
    int cl = 0;
    for (int n = n0; n < n1; ++n) {
        int g = batch[n];
        if (g != cur) {
            atomicAdd(&pool[cur * 64 + lane], acc);
            if (lane == 0) atomicAdd(&cnt[cur], (float)cl);
            acc = 0.f; cl = 0; cur = g;
        }
        acc += h3[(size_t)n * 64 + lane];
        cl++;
    }
    atomicAdd(&pool[cur * 64 + lane], acc);
    if (lane == 0) atomicAdd(&cnt[cur], (float)cl);
}

// Final head: out[g][c] = (pool[g]/cnt[g]) @ lin_W + lin_b
__global__ void head_kernel(const float* __restrict__ pool, const float* __restrict__ cnt,
                            const float* __restrict__ linW, const float* __restrict__ linb,
                            float* __restrict__ out) {
    int g = threadIdx.x >> 1;
    int c = threadIdx.x & 1;
    if (g < N_GRAPHS) {
        float inv = 1.0f / fmaxf(cnt[g], 1.0f);
        float acc = linb[c];
        for (int j = 0; j < 64; ++j) acc += pool[g * 64 + j] * inv * linW[j * 2 + c];
        out[g * 2 + c] = acc;
    }
}

// ---------------------------------------------------------------------------
extern "C" void kernel_launch(void* const* d_in, const int* in_sizes, int n_in,
                              void* d_out, int out_size, void* d_ws, size_t ws_size,
                              hipStream_t stream) {
    const float* x = (const float*)d_in[0];
    const int* edge_index = (const int*)d_in[1];
    const int* batch = (const int*)d_in[2];
    const float* bn_gamma = (const float*)d_in[3];
    const float* bn_beta = (const float*)d_in[4];
    const float* bn_mean = (const float*)d_in[5];
    const float* bn_var = (const float*)d_in[6];
    const float* W1_rel = (const float*)d_in[7];
    const float* b1_rel = (const float*)d_in[8];
    const float* W1_root = (const float*)d_in[9];
    const float* W2_rel = (const float*)d_in[10];
    const float* b2_rel = (const float*)d_in[11];
    const float* W2_root = (const float*)d_in[12];
    const float* W3_rel = (const float*)d_in[13];
    const float* b3_rel = (const float*)d_in[14];
    const float* W3_root = (const float*)d_in[15];
    const float* lin_W = (const float*)d_in[16];
    const float* lin_b = (const float*)d_in[17];
    float* out = (float*)d_out;

    const int* e_src = edge_index;
    const int* e_dst = edge_index + N_EDGES;

    // workspace layout
    float* ws_f = (float*)d_ws;
    float* h0 = ws_f;                       // 320000
    float* h1 = h0 + 320000;                // 5120000
    float* h2 = h1 + 5120000;               // 5120000
    float* pool = h2 + 5120000;             // 4096
    float* cnt = pool + 4096;               // 64
    int* deg = (int*)(cnt + 64);            // 80000
    int* rowstart = deg + 80000;            // 80001
    int* cursor = rowstart + 80001;         // 80000
    int* csr = cursor + 80000;              // 1280000
    int* bsum = csr + 1280000;              // 313
    int* boff = bsum + 512;                 // 313
    float* h3 = h1;                         // alias: h1 dead once h2 computed

    // zero the accumulators we rely on
    hipMemsetAsync(deg, 0, (size_t)N_NODES * sizeof(int), stream);
    hipMemsetAsync(pool, 0, (size_t)(4096 + 64) * sizeof(float), stream);

    // BN
    bn_kernel<<<(N_NODES * N_FEAT + 255) / 256, 256, 0, stream>>>(
        x, bn_gamma, bn_beta, bn_mean, bn_var, h0);

    // CSR build
    count_kernel<<<(N_EDGES + 255) / 256, 256, 0, stream>>>(e_dst, deg);
    scan_pass1<<<SCAN_NB, SCAN_CH, 0, stream>>>(deg, bsum);
    scan_pass2<<<1, 512, 0, stream>>>(bsum, boff);
    scan_pass3<<<SCAN_NB, SCAN_CH, 0, stream>>>(deg, boff, rowstart, cursor);
    fill_kernel<<<(N_EDGES + 255) / 256, 256, 0, stream>>>(e_src, e_dst, cursor, csr);

    // Layer 1: h1 = relu(conv(h0))
    layer1_kernel<<<512, 1024, 0, stream>>>(h0, h1, rowstart, csr, W1_rel, W1_root, b1_rel);
    // Layer 2: h2 = relu(conv(h1))
    layer64_kernel<<<512, 1024, 0, stream>>>(h1, h2, rowstart, csr, W2_rel, W2_root, b2_rel, 1);
    // Layer 3: h3 = conv(h2)   (no relu), h3 aliases h1
    layer64_kernel<<<512, 1024, 0, stream>>>(h2, h3, rowstart, csr, W3_rel, W3_root, b3_rel, 0);

    // Pool + head
    pool_kernel<<<256, 256, 0, stream>>>(h3, batch, pool, cnt);
    head_kernel<<<1, 128, 0, stream>>>(pool, cnt, lin_W, lin_b, out);
}

// Round 3
// 375.530 us; speedup vs baseline: 1.7960x; 1.3396x over previous
//
#include <hip/hip_runtime.h>
#include <hip/hip_bf16.h>

#define N_NODES 80000
#define N_EDGES 1280000
#define N_FEAT 4
#define HIDDEN 64
#define N_GRAPHS 64
#define BN_EPS 1e-5f

#define SCAN_CH 256
#define SCAN_NB ((N_NODES + SCAN_CH - 1) / SCAN_CH)   // 313

// ---------------------------------------------------------------------------
// BN (eval mode): h0[n][k] = (x - mean[k]) * gamma[k]*rsqrt(var[k]+eps) + beta[k]
__global__ void bn_kernel(const float* __restrict__ x,
                          const float* __restrict__ gamma,
                          const float* __restrict__ beta,
                          const float* __restrict__ mean,
                          const float* __restrict__ var,
                          float* __restrict__ h0) {
    int i = blockIdx.x * blockDim.x + threadIdx.x;
    if (i < N_NODES * N_FEAT) {
        int k = i & 3;
        float scale = gamma[k] * rsqrtf(var[k] + BN_EPS);
        h0[i] = (x[i] - mean[k]) * scale + beta[k];
    }
}

// ---------------------------------------------------------------------------
// CSR build: count in-degree per dst
__global__ void count_kernel(const int* __restrict__ dst, int* __restrict__ deg) {
    int e = blockIdx.x * blockDim.x + threadIdx.x;
    if (e < N_EDGES) atomicAdd(&deg[dst[e]], 1);
}

// Device-wide exclusive scan, pass 1: per-block reduce of deg chunks
__global__ void scan_pass1(const int* __restrict__ deg, int* __restrict__ bsum) {
    __shared__ int s[4];
    int i = blockIdx.x * SCAN_CH + threadIdx.x;
    int v = (i < N_NODES) ? deg[i] : 0;
#pragma unroll
    for (int off = 1; off < 64; off <<= 1) v += __shfl_xor(v, off);
    if ((threadIdx.x & 63) == 0) s[threadIdx.x >> 6] = v;
    __syncthreads();
    if (threadIdx.x == 0) bsum[blockIdx.x] = s[0] + s[1] + s[2] + s[3];
}

// pass 2: scan the 313 block sums (one small block) -> exclusive offsets
__global__ __launch_bounds__(512) void scan_pass2(const int* __restrict__ bsum,
                                                  int* __restrict__ boff) {
    __shared__ int s[512];
    const int t = threadIdx.x;
    int v = (t < SCAN_NB) ? bsum[t] : 0;
    s[t] = v;
    __syncthreads();
    for (int off = 1; off < 512; off <<= 1) {
        int u = (t >= off) ? s[t - off] : 0;
        __syncthreads();
        s[t] += u;
        __syncthreads();
    }
    if (t < SCAN_NB) boff[t] = s[t] - v;   // exclusive
}

// pass 3: block-local inclusive scan + block offset -> rowstart / cursor
__global__ void scan_pass3(const int* __restrict__ deg, const int* __restrict__ boff,
                           int* __restrict__ rowstart, int* __restrict__ cursor) {
    __shared__ int s[SCAN_CH];
    const int t = threadIdx.x;
    int i = blockIdx.x * SCAN_CH + t;
    int v = (i < N_NODES) ? deg[i] : 0;
    s[t] = v;
    __syncthreads();
    for (int off = 1; off < SCAN_CH; off <<= 1) {
        int u = (t >= off) ? s[t - off] : 0;
        __syncthreads();
        s[t] += u;
        __syncthreads();
    }
    if (i < N_NODES) {
        int excl = boff[blockIdx.x] + s[t] - v;
        rowstart[i] = excl;
        cursor[i] = excl;
        if (i == N_NODES - 1) rowstart[N_NODES] = boff[blockIdx.x] + s[t];
    }
}

// Fill CSR: csr_src[rowstart[dst] + pos] = src
__global__ void fill_kernel(const int* __restrict__ src, const int* __restrict__ dst,
                            int* __restrict__ cursor, int* __restrict__ csr) {
    int e = blockIdx.x * blockDim.x + threadIdx.x;
    if (e < N_EDGES) {
        int d = dst[e];
        int p = atomicAdd(&cursor[d], 1);
        csr[p] = src[e];
    }
}

// ---------------------------------------------------------------------------
// Layer 1 (in=4, out=64), fused aggregate + transform + relu.
__global__ __launch_bounds__(1024) void layer1_kernel(
        const float* __restrict__ h0, float* __restrict__ h1,
        const int* __restrict__ rowstart, const int* __restrict__ csr,
        const float* __restrict__ Wrel, const float* __restrict__ Wroot,
        const float* __restrict__ b) {
    const int lane = threadIdx.x & 63;
    const int wid = threadIdx.x >> 6;
    float wrel[4], wroot[4];
#pragma unroll
    for (int k = 0; k < 4; ++k) {
        wrel[k] = Wrel[k * 64 + lane];
        wroot[k] = Wroot[k * 64 + lane];
    }
    const float bj = b[lane];
    const int sub = lane >> 2;  // 0..15: which edge slot
    const int f = lane & 3;     // which feature
    const int nW = gridDim.x * 16;
    for (int n0 = blockIdx.x * 16 + wid; n0 < N_NODES; n0 += nW) {
        const int node = __builtin_amdgcn_readfirstlane(n0);
        const int e0 = rowstart[node], e1 = rowstart[node + 1];
        float part = 0.f;
        for (int e = e0 + sub; e < e1; e += 16) {
            int s = csr[e];
            part += h0[s * 4 + f];
        }
        part += __shfl_xor(part, 4);
        part += __shfl_xor(part, 8);
        part += __shfl_xor(part, 16);
        part += __shfl_xor(part, 32);
        float a0 = __shfl(part, 0), a1 = __shfl(part, 1);
        float a2 = __shfl(part, 2), a3 = __shfl(part, 3);
        float x0 = h0[node * 4 + 0], x1 = h0[node * 4 + 1];
        float x2 = h0[node * 4 + 2], x3 = h0[node * 4 + 3];
        float out = bj + a0 * wrel[0] + a1 * wrel[1] + a2 * wrel[2] + a3 * wrel[3]
                  + x0 * wroot[0] + x1 * wroot[1] + x2 * wroot[2] + x3 * wroot[3];
        h1[node * 64 + lane] = fmaxf(out, 0.f);
    }
}

// ---------------------------------------------------------------------------
// Layer with in=out=64, fused aggregate + transform (+ optional relu).
// Gather is unrolled x8/x4 with independent accumulators: 8 row-loads in
// flight per wave instead of 1 (latency-bound fix, r2).
__global__ __launch_bounds__(1024) void layer64_kernel(
        const float* __restrict__ hin, float* __restrict__ hout,
        const int* __restrict__ rowstart, const int* __restrict__ csr,
        const float* __restrict__ Wrel, const float* __restrict__ Wroot,
        const float* __restrict__ b, int relu) {
    __shared__ float sW[2][64][64];   // 32KB
    __shared__ float sV[16][2][64];   // per-wave staging: [agg, h]
    const int lane = threadIdx.x & 63;
    const int wid = threadIdx.x >> 6;
    for (int i = threadIdx.x; i < 64 * 64; i += 1024) {
        sW[0][i >> 6][i & 63] = Wrel[i];
        sW[1][i >> 6][i & 63] = Wroot[i];
    }
    __syncthreads();
    const float bj = b[lane];
    const int nW = gridDim.x * 16;
    for (int n0 = blockIdx.x * 16 + wid; n0 < N_NODES; n0 += nW) {
        const int node = __builtin_amdgcn_readfirstlane(n0);
        const int e0 = rowstart[node], e1 = rowstart[node + 1];
        float a0 = 0.f, a1 = 0.f, a2 = 0.f, a3 = 0.f;
        float a4 = 0.f, a5 = 0.f, a6 = 0.f, a7 = 0.f;
        int e = e0;
        for (; e + 8 <= e1; e += 8) {
            int s0 = csr[e + 0], s1 = csr[e + 1], s2 = csr[e + 2], s3 = csr[e + 3];
            int s4 = csr[e + 4], s5 = csr[e + 5], s6 = csr[e + 6], s7 = csr[e + 7];
            a0 += hin[(size_t)s0 * 64 + lane];
            a1 += hin[(size_t)s1 * 64 + lane];
            a2 += hin[(size_t)s2 * 64 + lane];
            a3 += hin[(size_t)s3 * 64 + lane];
            a4 += hin[(size_t)s4 * 64 + lane];
            a5 += hin[(size_t)s5 * 64 + lane];
            a6 += hin[(size_t)s6 * 64 + lane];
            a7 += hin[(size_t)s7 * 64 + lane];
        }
        if (e + 4 <= e1) {
            int s0 = csr[e + 0], s1 = csr[e + 1], s2 = csr[e + 2], s3 = csr[e + 3];
            a0 += hin[(size_t)s0 * 64 + lane];
            a1 += hin[(size_t)s1 * 64 + lane];
            a2 += hin[(size_t)s2 * 64 + lane];
            a3 += hin[(size_t)s3 * 64 + lane];
            e += 4;
        }
        for (; e < e1; ++e) {
            a0 += hin[(size_t)csr[e] * 64 + lane];
        }
        float agg = ((a0 + a1) + (a2 + a3)) + ((a4 + a5) + (a6 + a7));
        float hv = hin[(size_t)node * 64 + lane];
        sV[wid][0][lane] = agg;
        sV[wid][1][lane] = hv;
        // wave-synchronous: ensure the wave's own LDS writes have landed
        asm volatile("s_waitcnt lgkmcnt(0)" ::: "memory");
        float out = bj;
        const float4* aggv = (const float4*)&sV[wid][0][0];
        const float4* hvv = (const float4*)&sV[wid][1][0];
#pragma unroll
        for (int k4 = 0; k4 < 16; ++k4) {
            float4 v4 = aggv[k4];   // broadcast ds_read_b128 (free)
            float4 h4 = hvv[k4];
            int k = k4 * 4;
            out += v4.x * sW[0][k + 0][lane] + v4.y * sW[0][k + 1][lane]
                 + v4.z * sW[0][k + 2][lane] + v4.w * sW[0][k + 3][lane]
                 + h4.x * sW[1][k + 0][lane] + h4.y * sW[1][k + 1][lane]
                 + h4.z * sW[1][k + 2][lane] + h4.w * sW[1][k + 3][lane];
        }
        if (relu) out = fmaxf(out, 0.f);
        hout[(size_t)node * 64 + lane] = out;
    }
}

// ---------------------------------------------------------------------------
// Mean-pool per graph. batch is sorted; each wave takes a contiguous chunk,
// accumulates in registers, flushes with atomics only at graph boundaries.
__global__ void pool_kernel(const float* __restrict__ h3, const int* __restrict__ batch,
                            float* __restrict__ pool, float* __restrict__ cnt) {
    const int lane = threadIdx.x & 63;
    const int gw = (blockIdx.x * blockDim.x + threadIdx.x) >> 6;
    const int nW = (gridDim.x * blockDim.x) >> 6;
    const int chunk = (N_NODES + nW - 1) / nW;
    int n0 = gw * chunk;
    int n1 = n0 + chunk; if (n1 > N_NODES) n1 = N_NODES;
    if (n0 >= N_NODES) return;
    float acc = 0.f;
    int cur = batch[n0];
    int cl = 0;
    for (int n = n0; n < n1; ++n) {
        int g = batch[n];
        if (g != cur) {
            atomicAdd(&pool[cur * 64 + lane], acc);
            if (lane == 0) atomicAdd(&cnt[cur], (float)cl);
            acc = 0.f; cl = 0; cur = g;
        }
        acc += h3[(size_t)n * 64 + lane];
        cl++;
    }
    atomicAdd(&pool[cur * 64 + lane], acc);
    if (lane == 0) atomicAdd(&cnt[cur], (float)cl);
}

// Final head: out[g][c] = (pool[g]/cnt[g]) @ lin_W + lin_b
__global__ void head_kernel(const float* __restrict__ pool, const float* __restrict__ cnt,
                            const float* __restrict__ linW, const float* __restrict__ linb,
                            float* __restrict__ out) {
    int g = threadIdx.x >> 1;
    int c = threadIdx.x & 1;
    if (g < N_GRAPHS) {
        float inv = 1.0f / fmaxf(cnt[g], 1.0f);
        float acc = linb[c];
        for (int j = 0; j < 64; ++j) acc += pool[g * 64 + j] * inv * linW[j * 2 + c];
        out[g * 2 + c] = acc;
    }
}

// ---------------------------------------------------------------------------
extern "C" void kernel_launch(void* const* d_in, const int* in_sizes, int n_in,
                              void* d_out, int out_size, void* d_ws, size_t ws_size,
                              hipStream_t stream) {
    const float* x = (const float*)d_in[0];
    const int* edge_index = (const int*)d_in[1];
    const int* batch = (const int*)d_in[2];
    const float* bn_gamma = (const float*)d_in[3];
    const float* bn_beta = (const float*)d_in[4];
    const float* bn_mean = (const float*)d_in[5];
    const float* bn_var = (const float*)d_in[6];
    const float* W1_rel = (const float*)d_in[7];
    const float* b1_rel = (const float*)d_in[8];
    const float* W1_root = (const float*)d_in[9];
    const float* W2_rel = (const float*)d_in[10];
    const float* b2_rel = (const float*)d_in[11];
    const float* W2_root = (const float*)d_in[12];
    const float* W3_rel = (const float*)d_in[13];
    const float* b3_rel = (const float*)d_in[14];
    const float* W3_root = (const float*)d_in[15];
    const float* lin_W = (const float*)d_in[16];
    const float* lin_b = (const float*)d_in[17];
    float* out = (float*)d_out;

    const int* e_src = edge_index;
    const int* e_dst = edge_index + N_EDGES;

    // workspace layout
    float* ws_f = (float*)d_ws;
    float* h0 = ws_f;                       // 320000
    float* h1 = h0 + 320000;                // 5120000
    float* h2 = h1 + 5120000;               // 5120000
    float* pool = h2 + 5120000;             // 4096
    float* cnt = pool + 4096;               // 64
    int* deg = (int*)(cnt + 64);            // 80000
    int* rowstart = deg + 80000;            // 80001
    int* cursor = rowstart + 80001;         // 80000
    int* csr = cursor + 80000;              // 1280000
    int* bsum = csr + 1280000;              // 313
    int* boff = bsum + 512;                 // 313
    float* h3 = h1;                         // alias: h1 dead once h2 computed

    // zero the accumulators we rely on
    hipMemsetAsync(deg, 0, (size_t)N_NODES * sizeof(int), stream);
    hipMemsetAsync(pool, 0, (size_t)(4096 + 64) * sizeof(float), stream);

    // BN
    bn_kernel<<<(N_NODES * N_FEAT + 255) / 256, 256, 0, stream>>>(
        x, bn_gamma, bn_beta, bn_mean, bn_var, h0);

    // CSR build
    count_kernel<<<(N_EDGES + 255) / 256, 256, 0, stream>>>(e_dst, deg);
    scan_pass1<<<SCAN_NB, SCAN_CH, 0, stream>>>(deg, bsum);
    scan_pass2<<<1, 512, 0, stream>>>(bsum, boff);
    scan_pass3<<<SCAN_NB, SCAN_CH, 0, stream>>>(deg, boff, rowstart, cursor);
    fill_kernel<<<(N_EDGES + 255) / 256, 256, 0, stream>>>(e_src, e_dst, cursor, csr);

    // Layer 1: h1 = relu(conv(h0))
    layer1_kernel<<<512, 1024, 0, stream>>>(h0, h1, rowstart, csr, W1_rel, W1_root, b1_rel);
    // Layer 2: h2 = relu(conv(h1))
    layer64_kernel<<<512, 1024, 0, stream>>>(h1, h2, rowstart, csr, W2_rel, W2_root, b2_rel, 1);
    // Layer 3: h3 = conv(h2)   (no relu), h3 aliases h1
    layer64_kernel<<<512, 1024, 0, stream>>>(h2, h3, rowstart, csr, W3_rel, W3_root, b3_rel, 0);

    // Pool + head
    pool_kernel<<<256, 256, 0, stream>>>(h3, batch, pool, cnt);
    head_kernel<<<1, 128, 0, stream>>>(pool, cnt, lin_W, lin_b, out);
}

// Round 4
// 261.375 us; speedup vs baseline: 2.5804x; 1.4367x over previous
//
#include <hip/hip_runtime.h>
#include <hip/hip_bf16.h>

#define N_NODES 80000
#define N_EDGES 1280000
#define N_FEAT 4
#define HIDDEN 64
#define N_GRAPHS 64
#define BN_EPS 1e-5f

#define NBUCK 313          // ceil(80000 / 256); bucket b covers nodes [b*256, b*256+256)
#define BCAP 8000          // per-bucket pair capacity (mean 4090, sigma ~64 -> safe)
#define EPT 16             // edges per thread in bucket_kernel

// ---------------------------------------------------------------------------
// BN (eval mode)
__global__ void bn_kernel(const float* __restrict__ x,
                          const float* __restrict__ gamma,
                          const float* __restrict__ beta,
                          const float* __restrict__ mean,
                          const float* __restrict__ var,
                          float* __restrict__ h0) {
    int i = blockIdx.x * blockDim.x + threadIdx.x;
    if (i < N_NODES * N_FEAT) {
        int k = i & 3;
        float scale = gamma[k] * rsqrtf(var[k] + BN_EPS);
        h0[i] = (x[i] - mean[k]) * scale + beta[k];
    }
}

// ---------------------------------------------------------------------------
// Bucketed counting sort, pass 1: scatter (src,dst) pairs into per-bucket
// regions. LDS histogram + per-edge LDS rank; ONE global atomic claim per
// (block,bucket). Same-bucket edges of a block land consecutively -> dense
// line fills instead of the old 16x write amplification.
__global__ __launch_bounds__(256) void bucket_kernel(
        const int* __restrict__ src, const int* __restrict__ dst,
        int2* __restrict__ pairs, int* __restrict__ bcursor) {
    __shared__ int hist[NBUCK];
    __shared__ int base[NBUCK];
    for (int i = threadIdx.x; i < NBUCK; i += 256) hist[i] = 0;
    __syncthreads();
    const int e0 = blockIdx.x * (256 * EPT) + threadIdx.x;
    int d[EPT], r[EPT];
#pragma unroll
    for (int k = 0; k < EPT; ++k) {
        int e = e0 + k * 256;
        if (e < N_EDGES) {
            d[k] = dst[e];
            r[k] = atomicAdd(&hist[d[k] >> 8], 1);
        }
    }
    __syncthreads();
    for (int i = threadIdx.x; i < NBUCK; i += 256) {
        int c = hist[i];
        base[i] = c ? atomicAdd(&bcursor[i], c) : 0;
    }
    __syncthreads();
#pragma unroll
    for (int k = 0; k < EPT; ++k) {
        int e = e0 + k * 256;
        if (e < N_EDGES) {
            int b = d[k] >> 8;
            int pos = base[b] + r[k];
            if (pos < BCAP) pairs[(size_t)b * BCAP + pos] = make_int2(src[e], d[k]);
        }
    }
}

// pass 2: exclusive scan of the 313 bucket counts -> bucket bases
__global__ __launch_bounds__(512) void bucket_scan_kernel(
        const int* __restrict__ bcursor, int* __restrict__ bbase,
        int* __restrict__ rowstart) {
    __shared__ int s[512];
    const int t = threadIdx.x;
    int v = (t < NBUCK) ? min(bcursor[t], BCAP) : 0;
    s[t] = v;
    __syncthreads();
    for (int off = 1; off < 512; off <<= 1) {
        int u = (t >= off) ? s[t - off] : 0;
        __syncthreads();
        s[t] += u;
        __syncthreads();
    }
    if (t < NBUCK) bbase[t] = s[t] - v;          // exclusive
    if (t == NBUCK - 1) rowstart[N_NODES] = s[t]; // == N_EDGES
}

// pass 3: per bucket, build node-level rowstart + csr. All scattered csr
// writes land inside the bucket's contiguous ~16KB window (L2 resident).
__global__ __launch_bounds__(256) void csr_build_kernel(
        const int2* __restrict__ pairs, const int* __restrict__ bcursor,
        const int* __restrict__ bbase,
        int* __restrict__ rowstart, int* __restrict__ csr) {
    __shared__ int degl[256];
    __shared__ int pref[256];
    __shared__ int curs[256];
    const int b = blockIdx.x;
    const int t = threadIdx.x;
    const int cnt = min(bcursor[b], BCAP);
    const int base = bbase[b];
    degl[t] = 0;
    __syncthreads();
    const int2* pb = pairs + (size_t)b * BCAP;
    for (int i = t; i < cnt; i += 256) {
        atomicAdd(&degl[pb[i].y & 255], 1);
    }
    __syncthreads();
    int v = degl[t];
    pref[t] = v;
    __syncthreads();
    for (int off = 1; off < 256; off <<= 1) {
        int u = (t >= off) ? pref[t - off] : 0;
        __syncthreads();
        pref[t] += u;
        __syncthreads();
    }
    int excl = pref[t] - v;   // exclusive prefix within bucket
    int node = b * 256 + t;
    if (node < N_NODES) rowstart[node] = base + excl;
    curs[t] = excl;
    __syncthreads();
    for (int i = t; i < cnt; i += 256) {
        int2 p = pb[i];
        int pos = atomicAdd(&curs[p.y & 255], 1);
        csr[base + pos] = p.x;
    }
}

// ---------------------------------------------------------------------------
// Layer 1 (in=4, out=64), fused aggregate + transform + relu.
__global__ __launch_bounds__(1024) void layer1_kernel(
        const float* __restrict__ h0, float* __restrict__ h1,
        const int* __restrict__ rowstart, const int* __restrict__ csr,
        const float* __restrict__ Wrel, const float* __restrict__ Wroot,
        const float* __restrict__ b) {
    const int lane = threadIdx.x & 63;
    const int wid = threadIdx.x >> 6;
    float wrel[4], wroot[4];
#pragma unroll
    for (int k = 0; k < 4; ++k) {
        wrel[k] = Wrel[k * 64 + lane];
        wroot[k] = Wroot[k * 64 + lane];
    }
    const float bj = b[lane];
    const int sub = lane >> 2;  // 0..15: which edge slot
    const int f = lane & 3;     // which feature
    const int nW = gridDim.x * 16;
    for (int n0 = blockIdx.x * 16 + wid; n0 < N_NODES; n0 += nW) {
        const int node = __builtin_amdgcn_readfirstlane(n0);
        const int e0 = rowstart[node], e1 = rowstart[node + 1];
        float part = 0.f;
        for (int e = e0 + sub; e < e1; e += 16) {
            int s = csr[e];
            part += h0[s * 4 + f];
        }
        part += __shfl_xor(part, 4);
        part += __shfl_xor(part, 8);
        part += __shfl_xor(part, 16);
        part += __shfl_xor(part, 32);
        float a0 = __shfl(part, 0), a1 = __shfl(part, 1);
        float a2 = __shfl(part, 2), a3 = __shfl(part, 3);
        float x0 = h0[node * 4 + 0], x1 = h0[node * 4 + 1];
        float x2 = h0[node * 4 + 2], x3 = h0[node * 4 + 3];
        float out = bj + a0 * wrel[0] + a1 * wrel[1] + a2 * wrel[2] + a3 * wrel[3]
                  + x0 * wroot[0] + x1 * wroot[1] + x2 * wroot[2] + x3 * wroot[3];
        h1[node * 64 + lane] = fmaxf(out, 0.f);
    }
}

// ---------------------------------------------------------------------------
// Layer with in=out=64, fused aggregate + transform (+ optional relu).
// Gather unrolled x8/x4 with independent accumulators (r2 fix).
__global__ __launch_bounds__(1024) void layer64_kernel(
        const float* __restrict__ hin, float* __restrict__ hout,
        const int* __restrict__ rowstart, const int* __restrict__ csr,
        const float* __restrict__ Wrel, const float* __restrict__ Wroot,
        const float* __restrict__ b, int relu) {
    __shared__ float sW[2][64][64];   // 32KB
    __shared__ float sV[16][2][64];   // per-wave staging: [agg, h]
    const int lane = threadIdx.x & 63;
    const int wid = threadIdx.x >> 6;
    for (int i = threadIdx.x; i < 64 * 64; i += 1024) {
        sW[0][i >> 6][i & 63] = Wrel[i];
        sW[1][i >> 6][i & 63] = Wroot[i];
    }
    __syncthreads();
    const float bj = b[lane];
    const int nW = gridDim.x * 16;
    for (int n0 = blockIdx.x * 16 + wid; n0 < N_NODES; n0 += nW) {
        const int node = __builtin_amdgcn_readfirstlane(n0);
        const int e0 = rowstart[node], e1 = rowstart[node + 1];
        float a0 = 0.f, a1 = 0.f, a2 = 0.f, a3 = 0.f;
        float a4 = 0.f, a5 = 0.f, a6 = 0.f, a7 = 0.f;
        int e = e0;
        for (; e + 8 <= e1; e += 8) {
            int s0 = csr[e + 0], s1 = csr[e + 1], s2 = csr[e + 2], s3 = csr[e + 3];
            int s4 = csr[e + 4], s5 = csr[e + 5], s6 = csr[e + 6], s7 = csr[e + 7];
            a0 += hin[(size_t)s0 * 64 + lane];
            a1 += hin[(size_t)s1 * 64 + lane];
            a2 += hin[(size_t)s2 * 64 + lane];
            a3 += hin[(size_t)s3 * 64 + lane];
            a4 += hin[(size_t)s4 * 64 + lane];
            a5 += hin[(size_t)s5 * 64 + lane];
            a6 += hin[(size_t)s6 * 64 + lane];
            a7 += hin[(size_t)s7 * 64 + lane];
        }
        if (e + 4 <= e1) {
            int s0 = csr[e + 0], s1 = csr[e + 1], s2 = csr[e + 2], s3 = csr[e + 3];
            a0 += hin[(size_t)s0 * 64 + lane];
            a1 += hin[(size_t)s1 * 64 + lane];
            a2 += hin[(size_t)s2 * 64 + lane];
            a3 += hin[(size_t)s3 * 64 + lane];
            e += 4;
        }
        for (; e < e1; ++e) {
            a0 += hin[(size_t)csr[e] * 64 + lane];
        }
        float agg = ((a0 + a1) + (a2 + a3)) + ((a4 + a5) + (a6 + a7));
        float hv = hin[(size_t)node * 64 + lane];
        sV[wid][0][lane] = agg;
        sV[wid][1][lane] = hv;
        asm volatile("s_waitcnt lgkmcnt(0)" ::: "memory");
        float out = bj;
        const float4* aggv = (const float4*)&sV[wid][0][0];
        const float4* hvv = (const float4*)&sV[wid][1][0];
#pragma unroll
        for (int k4 = 0; k4 < 16; ++k4) {
            float4 v4 = aggv[k4];   // broadcast ds_read_b128 (free)
            float4 h4 = hvv[k4];
            int k = k4 * 4;
            out += v4.x * sW[0][k + 0][lane] + v4.y * sW[0][k + 1][lane]
                 + v4.z * sW[0][k + 2][lane] + v4.w * sW[0][k + 3][lane]
                 + h4.x * sW[1][k + 0][lane] + h4.y * sW[1][k + 1][lane]
                 + h4.z * sW[1][k + 2][lane] + h4.w * sW[1][k + 3][lane];
        }
        if (relu) out = fmaxf(out, 0.f);
        hout[(size_t)node * 64 + lane] = out;
    }
}

// ---------------------------------------------------------------------------
// Mean-pool per graph (batch sorted: register accumulation, atomic flush
// only at graph boundaries).
__global__ void pool_kernel(const float* __restrict__ h3, const int* __restrict__ batch,
                            float* __restrict__ pool, float* __restrict__ cnt) {
    const int lane = threadIdx.x & 63;
    const int gw = (blockIdx.x * blockDim.x + threadIdx.x) >> 6;
    const int nW = (gridDim.x * blockDim.x) >> 6;
    const int chunk = (N_NODES + nW - 1) / nW;
    int n0 = gw * chunk;
    int n1 = n0 + chunk; if (n1 > N_NODES) n1 = N_NODES;
    if (n0 >= N_NODES) return;
    float acc = 0.f;
    int cur = batch[n0];
    int cl = 0;
    for (int n = n0; n < n1; ++n) {
        int g = batch[n];
        if (g != cur) {
            atomicAdd(&pool[cur * 64 + lane], acc);
            if (lane == 0) atomicAdd(&cnt[cur], (float)cl);
            acc = 0.f; cl = 0; cur = g;
        }
        acc += h3[(size_t)n * 64 + lane];
        cl++;
    }
    atomicAdd(&pool[cur * 64 + lane], acc);
    if (lane == 0) atomicAdd(&cnt[cur], (float)cl);
}

// Final head
__global__ void head_kernel(const float* __restrict__ pool, const float* __restrict__ cnt,
                            const float* __restrict__ linW, const float* __restrict__ linb,
                            float* __restrict__ out) {
    int g = threadIdx.x >> 1;
    int c = threadIdx.x & 1;
    if (g < N_GRAPHS) {
        float inv = 1.0f / fmaxf(cnt[g], 1.0f);
        float acc = linb[c];
        for (int j = 0; j < 64; ++j) acc += pool[g * 64 + j] * inv * linW[j * 2 + c];
        out[g * 2 + c] = acc;
    }
}

// ---------------------------------------------------------------------------
extern "C" void kernel_launch(void* const* d_in, const int* in_sizes, int n_in,
                              void* d_out, int out_size, void* d_ws, size_t ws_size,
                              hipStream_t stream) {
    const float* x = (const float*)d_in[0];
    const int* edge_index = (const int*)d_in[1];
    const int* batch = (const int*)d_in[2];
    const float* bn_gamma = (const float*)d_in[3];
    const float* bn_beta = (const float*)d_in[4];
    const float* bn_mean = (const float*)d_in[5];
    const float* bn_var = (const float*)d_in[6];
    const float* W1_rel = (const float*)d_in[7];
    const float* b1_rel = (const float*)d_in[8];
    const float* W1_root = (const float*)d_in[9];
    const float* W2_rel = (const float*)d_in[10];
    const float* b2_rel = (const float*)d_in[11];
    const float* W2_root = (const float*)d_in[12];
    const float* W3_rel = (const float*)d_in[13];
    const float* b3_rel = (const float*)d_in[14];
    const float* W3_root = (const float*)d_in[15];
    const float* lin_W = (const float*)d_in[16];
    const float* lin_b = (const float*)d_in[17];
    float* out = (float*)d_out;

    const int* e_src = edge_index;
    const int* e_dst = edge_index + N_EDGES;

    // workspace layout
    float* ws_f = (float*)d_ws;
    float* h0 = ws_f;                       // 320000 floats
    float* h1 = h0 + 320000;                // 5120000
    float* h2 = h1 + 5120000;               // 5120000 (aliases pairs during CSR build)
    float* pool = h2 + 5120000;             // 4096
    float* cnt = pool + 4096;               // 64
    int* bcursor = (int*)(cnt + 64);        // 320
    int* bbase = bcursor + 320;             // 320
    int* rowstart = bbase + 320;            // 80001
    int* csr = rowstart + 80001;            // 1280000
    int2* pairs = (int2*)h2;                // NBUCK*BCAP int2 = 20.03MB <= 20.48MB
    float* h3 = h1;                         // alias: h1 dead once h2 computed

    hipMemsetAsync(bcursor, 0, (size_t)NBUCK * sizeof(int), stream);
    hipMemsetAsync(pool, 0, (size_t)(4096 + 64) * sizeof(float), stream);

    // BN
    bn_kernel<<<(N_NODES * N_FEAT + 255) / 256, 256, 0, stream>>>(
        x, bn_gamma, bn_beta, bn_mean, bn_var, h0);

    // CSR build (bucketed counting sort)
    bucket_kernel<<<(N_EDGES + 256 * EPT - 1) / (256 * EPT), 256, 0, stream>>>(
        e_src, e_dst, pairs, bcursor);
    bucket_scan_kernel<<<1, 512, 0, stream>>>(bcursor, bbase, rowstart);
    csr_build_kernel<<<NBUCK, 256, 0, stream>>>(pairs, bcursor, bbase, rowstart, csr);

    // Layer 1: h1 = relu(conv(h0))
    layer1_kernel<<<512, 1024, 0, stream>>>(h0, h1, rowstart, csr, W1_rel, W1_root, b1_rel);
    // Layer 2: h2 = relu(conv(h1))   (pairs buffer is dead from here on)
    layer64_kernel<<<512, 1024, 0, stream>>>(h1, h2, rowstart, csr, W2_rel, W2_root, b2_rel, 1);
    // Layer 3: h3 = conv(h2)   (no relu), h3 aliases h1
    layer64_kernel<<<512, 1024, 0, stream>>>(h2, h3, rowstart, csr, W3_rel, W3_root, b3_rel, 0);

    // Pool + head
    pool_kernel<<<256, 256, 0, stream>>>(h3, batch, pool, cnt);
    head_kernel<<<1, 128, 0, stream>>>(pool, cnt, lin_W, lin_b, out);
}

// Round 5
// 249.888 us; speedup vs baseline: 2.6990x; 1.0460x over previous
//
#include <hip/hip_runtime.h>
#include <hip/hip_bf16.h>

#define N_NODES 80000
#define N_EDGES 1280000
#define N_FEAT 4
#define HIDDEN 64
#define N_GRAPHS 64
#define BN_EPS 1e-5f

#define NBUCK 313          // ceil(80000 / 256); bucket b covers nodes [b*256, b*256+256)
#define BCAP 8000          // per-bucket pair capacity (mean 4090, sigma ~64 -> safe)
#define EPT 16             // edges per thread in bucket_kernel

typedef unsigned short ushort_t;

// bf16 <-> f32 (RNE pack; NaN not expected in this workload)
__device__ __forceinline__ float bf2f(ushort_t v) {
    return __uint_as_float(((unsigned)v) << 16);
}
__device__ __forceinline__ ushort_t f2bf(float f) {
    unsigned u = __float_as_uint(f);
    u += 0x7FFFu + ((u >> 16) & 1u);
    return (ushort_t)(u >> 16);
}

// ---------------------------------------------------------------------------
// BN (eval mode)
__global__ void bn_kernel(const float* __restrict__ x,
                          const float* __restrict__ gamma,
                          const float* __restrict__ beta,
                          const float* __restrict__ mean,
                          const float* __restrict__ var,
                          float* __restrict__ h0) {
    int i = blockIdx.x * blockDim.x + threadIdx.x;
    if (i < N_NODES * N_FEAT) {
        int k = i & 3;
        float scale = gamma[k] * rsqrtf(var[k] + BN_EPS);
        h0[i] = (x[i] - mean[k]) * scale + beta[k];
    }
}

// ---------------------------------------------------------------------------
// Bucketed counting sort, pass 1 (r3): scatter (src,dst) into per-bucket
// regions; one global atomic claim per (block,bucket).
__global__ __launch_bounds__(256) void bucket_kernel(
        const int* __restrict__ src, const int* __restrict__ dst,
        int2* __restrict__ pairs, int* __restrict__ bcursor) {
    __shared__ int hist[NBUCK];
    __shared__ int base[NBUCK];
    for (int i = threadIdx.x; i < NBUCK; i += 256) hist[i] = 0;
    __syncthreads();
    const int e0 = blockIdx.x * (256 * EPT) + threadIdx.x;
    int d[EPT], r[EPT];
#pragma unroll
    for (int k = 0; k < EPT; ++k) {
        int e = e0 + k * 256;
        if (e < N_EDGES) {
            d[k] = dst[e];
            r[k] = atomicAdd(&hist[d[k] >> 8], 1);
        }
    }
    __syncthreads();
    for (int i = threadIdx.x; i < NBUCK; i += 256) {
        int c = hist[i];
        base[i] = c ? atomicAdd(&bcursor[i], c) : 0;
    }
    __syncthreads();
#pragma unroll
    for (int k = 0; k < EPT; ++k) {
        int e = e0 + k * 256;
        if (e < N_EDGES) {
            int b = d[k] >> 8;
            int pos = base[b] + r[k];
            if (pos < BCAP) pairs[(size_t)b * BCAP + pos] = make_int2(src[e], d[k]);
        }
    }
}

// pass 2: exclusive scan of the 313 bucket counts -> bucket bases
__global__ __launch_bounds__(512) void bucket_scan_kernel(
        const int* __restrict__ bcursor, int* __restrict__ bbase,
        int* __restrict__ rowstart) {
    __shared__ int s[512];
    const int t = threadIdx.x;
    int v = (t < NBUCK) ? min(bcursor[t], BCAP) : 0;
    s[t] = v;
    __syncthreads();
    for (int off = 1; off < 512; off <<= 1) {
        int u = (t >= off) ? s[t - off] : 0;
        __syncthreads();
        s[t] += u;
        __syncthreads();
    }
    if (t < NBUCK) bbase[t] = s[t] - v;          // exclusive
    if (t == NBUCK - 1) rowstart[N_NODES] = s[t]; // == N_EDGES
}

// pass 3: per bucket, node-level rowstart + csr (writes stay in a contiguous
// ~16KB L2-resident window).
__global__ __launch_bounds__(256) void csr_build_kernel(
        const int2* __restrict__ pairs, const int* __restrict__ bcursor,
        const int* __restrict__ bbase,
        int* __restrict__ rowstart, int* __restrict__ csr) {
    __shared__ int degl[256];
    __shared__ int pref[256];
    __shared__ int curs[256];
    const int b = blockIdx.x;
    const int t = threadIdx.x;
    const int cnt = min(bcursor[b], BCAP);
    const int base = bbase[b];
    degl[t] = 0;
    __syncthreads();
    const int2* pb = pairs + (size_t)b * BCAP;
    for (int i = t; i < cnt; i += 256) {
        atomicAdd(&degl[pb[i].y & 255], 1);
    }
    __syncthreads();
    int v = degl[t];
    pref[t] = v;
    __syncthreads();
    for (int off = 1; off < 256; off <<= 1) {
        int u = (t >= off) ? pref[t - off] : 0;
        __syncthreads();
        pref[t] += u;
        __syncthreads();
    }
    int excl = pref[t] - v;   // exclusive prefix within bucket
    int node = b * 256 + t;
    if (node < N_NODES) rowstart[node] = base + excl;
    curs[t] = excl;
    __syncthreads();
    for (int i = t; i < cnt; i += 256) {
        int2 p = pb[i];
        int pos = atomicAdd(&curs[p.y & 255], 1);
        csr[base + pos] = p.x;
    }
}

// ---------------------------------------------------------------------------
// Layer 1 (in=4, out=64): fp32 h0 in, bf16 h1 out.
__global__ __launch_bounds__(1024) void layer1_kernel(
        const float* __restrict__ h0, ushort_t* __restrict__ h1,
        const int* __restrict__ rowstart, const int* __restrict__ csr,
        const float* __restrict__ Wrel, const float* __restrict__ Wroot,
        const float* __restrict__ b) {
    const int lane = threadIdx.x & 63;
    const int wid = threadIdx.x >> 6;
    float wrel[4], wroot[4];
#pragma unroll
    for (int k = 0; k < 4; ++k) {
        wrel[k] = Wrel[k * 64 + lane];
        wroot[k] = Wroot[k * 64 + lane];
    }
    const float bj = b[lane];
    const int sub = lane >> 2;  // 0..15: which edge slot
    const int f = lane & 3;     // which feature
    const int nW = gridDim.x * 16;
    for (int n0 = blockIdx.x * 16 + wid; n0 < N_NODES; n0 += nW) {
        const int node = __builtin_amdgcn_readfirstlane(n0);
        const int e0 = rowstart[node], e1 = rowstart[node + 1];
        float part = 0.f;
        for (int e = e0 + sub; e < e1; e += 16) {
            int s = csr[e];
            part += h0[s * 4 + f];
        }
        part += __shfl_xor(part, 4);
        part += __shfl_xor(part, 8);
        part += __shfl_xor(part, 16);
        part += __shfl_xor(part, 32);
        float a0 = __shfl(part, 0), a1 = __shfl(part, 1);
        float a2 = __shfl(part, 2), a3 = __shfl(part, 3);
        float x0 = h0[node * 4 + 0], x1 = h0[node * 4 + 1];
        float x2 = h0[node * 4 + 2], x3 = h0[node * 4 + 3];
        float out = bj + a0 * wrel[0] + a1 * wrel[1] + a2 * wrel[2] + a3 * wrel[3]
                  + x0 * wroot[0] + x1 * wroot[1] + x2 * wroot[2] + x3 * wroot[3];
        h1[(size_t)node * 64 + lane] = f2bf(fmaxf(out, 0.f));
    }
}

// ---------------------------------------------------------------------------
// Layer in=out=64: bf16 features in/out, fp32 accumulate. Gather unrolled
// x8/x4 (r2); bf16 rows halve the dominant L2-miss traffic (r4).
__global__ __launch_bounds__(1024) void layer64_kernel(
        const ushort_t* __restrict__ hin, ushort_t* __restrict__ hout,
        const int* __restrict__ rowstart, const int* __restrict__ csr,
        const float* __restrict__ Wrel, const float* __restrict__ Wroot,
        const float* __restrict__ b, int relu) {
    __shared__ float sW[2][64][64];   // 32KB
    __shared__ float sV[16][2][64];   // per-wave staging: [agg, h]
    const int lane = threadIdx.x & 63;
    const int wid = threadIdx.x >> 6;
    for (int i = threadIdx.x; i < 64 * 64; i += 1024) {
        sW[0][i >> 6][i & 63] = Wrel[i];
        sW[1][i >> 6][i & 63] = Wroot[i];
    }
    __syncthreads();
    const float bj = b[lane];
    const int nW = gridDim.x * 16;
    for (int n0 = blockIdx.x * 16 + wid; n0 < N_NODES; n0 += nW) {
        const int node = __builtin_amdgcn_readfirstlane(n0);
        const int e0 = rowstart[node], e1 = rowstart[node + 1];
        float a0 = 0.f, a1 = 0.f, a2 = 0.f, a3 = 0.f;
        float a4 = 0.f, a5 = 0.f, a6 = 0.f, a7 = 0.f;
        int e = e0;
        for (; e + 8 <= e1; e += 8) {
            int s0 = csr[e + 0], s1 = csr[e + 1], s2 = csr[e + 2], s3 = csr[e + 3];
            int s4 = csr[e + 4], s5 = csr[e + 5], s6 = csr[e + 6], s7 = csr[e + 7];
            ushort_t v0 = hin[(size_t)s0 * 64 + lane];
            ushort_t v1 = hin[(size_t)s1 * 64 + lane];
            ushort_t v2 = hin[(size_t)s2 * 64 + lane];
            ushort_t v3 = hin[(size_t)s3 * 64 + lane];
            ushort_t v4 = hin[(size_t)s4 * 64 + lane];
            ushort_t v5 = hin[(size_t)s5 * 64 + lane];
            ushort_t v6 = hin[(size_t)s6 * 64 + lane];
            ushort_t v7 = hin[(size_t)s7 * 64 + lane];
            a0 += bf2f(v0); a1 += bf2f(v1); a2 += bf2f(v2); a3 += bf2f(v3);
            a4 += bf2f(v4); a5 += bf2f(v5); a6 += bf2f(v6); a7 += bf2f(v7);
        }
        if (e + 4 <= e1) {
            int s0 = csr[e + 0], s1 = csr[e + 1], s2 = csr[e + 2], s3 = csr[e + 3];
            ushort_t v0 = hin[(size_t)s0 * 64 + lane];
            ushort_t v1 = hin[(size_t)s1 * 64 + lane];
            ushort_t v2 = hin[(size_t)s2 * 64 + lane];
            ushort_t v3 = hin[(size_t)s3 * 64 + lane];
            a0 += bf2f(v0); a1 += bf2f(v1); a2 += bf2f(v2); a3 += bf2f(v3);
            e += 4;
        }
        for (; e < e1; ++e) {
            a0 += bf2f(hin[(size_t)csr[e] * 64 + lane]);
        }
        float agg = ((a0 + a1) + (a2 + a3)) + ((a4 + a5) + (a6 + a7));
        float hv = bf2f(hin[(size_t)node * 64 + lane]);
        sV[wid][0][lane] = agg;
        sV[wid][1][lane] = hv;
        asm volatile("s_waitcnt lgkmcnt(0)" ::: "memory");
        float out = bj;
        const float4* aggv = (const float4*)&sV[wid][0][0];
        const float4* hvv = (const float4*)&sV[wid][1][0];
#pragma unroll
        for (int k4 = 0; k4 < 16; ++k4) {
            float4 v4 = aggv[k4];   // broadcast ds_read_b128 (free)
            float4 h4 = hvv[k4];
            int k = k4 * 4;
            out += v4.x * sW[0][k + 0][lane] + v4.y * sW[0][k + 1][lane]
                 + v4.z * sW[0][k + 2][lane] + v4.w * sW[0][k + 3][lane]
                 + h4.x * sW[1][k + 0][lane] + h4.y * sW[1][k + 1][lane]
                 + h4.z * sW[1][k + 2][lane] + h4.w * sW[1][k + 3][lane];
        }
        if (relu) out = fmaxf(out, 0.f);
        hout[(size_t)node * 64 + lane] = f2bf(out);
    }
}

// ---------------------------------------------------------------------------
// Mean-pool per graph; bf16 h3 in, fp32 accumulation.
__global__ void pool_kernel(const ushort_t* __restrict__ h3, const int* __restrict__ batch,
                            float* __restrict__ pool, float* __restrict__ cnt) {
    const int lane = threadIdx.x & 63;
    const int gw = (blockIdx.x * blockDim.x + threadIdx.x) >> 6;
    const int nW = (gridDim.x * blockDim.x) >> 6;
    const int chunk = (N_NODES + nW - 1) / nW;
    int n0 = gw * chunk;
    int n1 = n0 + chunk; if (n1 > N_NODES) n1 = N_NODES;
    if (n0 >= N_NODES) return;
    float acc = 0.f;
    int cur = batch[n0];
    int cl = 0;
    for (int n = n0; n < n1; ++n) {
        int g = batch[n];
        if (g != cur) {
            atomicAdd(&pool[cur * 64 + lane], acc);
            if (lane == 0) atomicAdd(&cnt[cur], (float)cl);
            acc = 0.f; cl = 0; cur = g;
        }
        acc += bf2f(h3[(size_t)n * 64 + lane]);
        cl++;
    }
    atomicAdd(&pool[cur * 64 + lane], acc);
    if (lane == 0) atomicAdd(&cnt[cur], (float)cl);
}

// Final head
__global__ void head_kernel(const float* __restrict__ pool, const float* __restrict__ cnt,
                            const float* __restrict__ linW, const float* __restrict__ linb,
                            float* __restrict__ out) {
    int g = threadIdx.x >> 1;
    int c = threadIdx.x & 1;
    if (g < N_GRAPHS) {
        float inv = 1.0f / fmaxf(cnt[g], 1.0f);
        float acc = linb[c];
        for (int j = 0; j < 64; ++j) acc += pool[g * 64 + j] * inv * linW[j * 2 + c];
        out[g * 2 + c] = acc;
    }
}

// ---------------------------------------------------------------------------
extern "C" void kernel_launch(void* const* d_in, const int* in_sizes, int n_in,
                              void* d_out, int out_size, void* d_ws, size_t ws_size,
                              hipStream_t stream) {
    const float* x = (const float*)d_in[0];
    const int* edge_index = (const int*)d_in[1];
    const int* batch = (const int*)d_in[2];
    const float* bn_gamma = (const float*)d_in[3];
    const float* bn_beta = (const float*)d_in[4];
    const float* bn_mean = (const float*)d_in[5];
    const float* bn_var = (const float*)d_in[6];
    const float* W1_rel = (const float*)d_in[7];
    const float* b1_rel = (const float*)d_in[8];
    const float* W1_root = (const float*)d_in[9];
    const float* W2_rel = (const float*)d_in[10];
    const float* b2_rel = (const float*)d_in[11];
    const float* W2_root = (const float*)d_in[12];
    const float* W3_rel = (const float*)d_in[13];
    const float* b3_rel = (const float*)d_in[14];
    const float* W3_root = (const float*)d_in[15];
    const float* lin_W = (const float*)d_in[16];
    const float* lin_b = (const float*)d_in[17];
    float* out = (float*)d_out;

    const int* e_src = edge_index;
    const int* e_dst = edge_index + N_EDGES;

    // workspace layout (bf16 features: h buffers are ushort)
    float* ws_f = (float*)d_ws;
    float* h0 = ws_f;                           // 320000 f32 = 1.28MB
    ushort_t* h1 = (ushort_t*)(h0 + 320000);    // 5.12M bf16 = 10.24MB
    ushort_t* h2 = h1 + 5120000;                // 5.12M bf16 = 10.24MB
    float* pool = (float*)(h2 + 5120000);       // 4096 f32
    float* cnt = pool + 4096;                   // 64
    int* bcursor = (int*)(cnt + 64);            // 320
    int* bbase = bcursor + 320;                 // 320
    int* rowstart = bbase + 320;                // 80001
    int* csr = rowstart + 80001;                // 1280000
    int2* pairs = (int2*)h1;                    // 20.03MB, aliases h1+h2 (dead before layer1)
    ushort_t* h3 = h1;                          // alias: h1 dead once h2 computed

    hipMemsetAsync(bcursor, 0, (size_t)NBUCK * sizeof(int), stream);
    hipMemsetAsync(pool, 0, (size_t)(4096 + 64) * sizeof(float), stream);

    // BN
    bn_kernel<<<(N_NODES * N_FEAT + 255) / 256, 256, 0, stream>>>(
        x, bn_gamma, bn_beta, bn_mean, bn_var, h0);

    // CSR build (bucketed counting sort)
    bucket_kernel<<<(N_EDGES + 256 * EPT - 1) / (256 * EPT), 256, 0, stream>>>(
        e_src, e_dst, pairs, bcursor);
    bucket_scan_kernel<<<1, 512, 0, stream>>>(bcursor, bbase, rowstart);
    csr_build_kernel<<<NBUCK, 256, 0, stream>>>(pairs, bcursor, bbase, rowstart, csr);

    // Layer 1: h1 = relu(conv(h0))
    layer1_kernel<<<512, 1024, 0, stream>>>(h0, h1, rowstart, csr, W1_rel, W1_root, b1_rel);
    // Layer 2: h2 = relu(conv(h1))
    layer64_kernel<<<512, 1024, 0, stream>>>(h1, h2, rowstart, csr, W2_rel, W2_root, b2_rel, 1);
    // Layer 3: h3 = conv(h2)   (no relu), h3 aliases h1
    layer64_kernel<<<512, 1024, 0, stream>>>(h2, h3, rowstart, csr, W3_rel, W3_root, b3_rel, 0);

    // Pool + head
    pool_kernel<<<256, 256, 0, stream>>>(h3, batch, pool, cnt);
    head_kernel<<<1, 128, 0, stream>>>(pool, cnt, lin_W, lin_b, out);
}